// Round 1
// baseline (1159.385 us; speedup 1.0000x reference)
//
#include <hip/hip_runtime.h>
#include <cstdint>
#include <cstddef>

#define EPS_F 1e-6f

// ---------- bf16 helpers ----------
__device__ inline unsigned short f2bf(float f) {
    union { float f; unsigned u; } v; v.f = f;
    unsigned r = v.u + 0x7fffu + ((v.u >> 16) & 1u);   // RNE
    return (unsigned short)(r >> 16);
}
__device__ inline float bf2f(unsigned short u) {
    union { unsigned u; float f; } v; v.u = ((unsigned)u) << 16; return v.f;
}

typedef __attribute__((ext_vector_type(8))) __bf16 bf16x8;
typedef __attribute__((ext_vector_type(8))) short short8;
typedef __attribute__((ext_vector_type(4))) float floatx4;

__device__ inline void async_load16(const void* g, void* l) {
    __builtin_amdgcn_global_load_lds((const __attribute__((address_space(1))) void*)g,
                                     (__attribute__((address_space(3))) void*)l,
                                     16, 0, 0);
}

// ---------- cast fp32 -> bf16 (vectorized) ----------
__global__ void cast_x_kernel(const float* __restrict__ in, unsigned short* __restrict__ out, int n4) {
    int i = blockIdx.x * blockDim.x + threadIdx.x;
    if (i < n4) {
        float4 v = ((const float4*)in)[i];
        ushort4 o;
        o.x = f2bf(v.x); o.y = f2bf(v.y); o.z = f2bf(v.z); o.w = f2bf(v.w);
        ((ushort4*)out)[i] = o;
    }
}

// ---------- transpose + cast: W (K x N fp32, row-major) -> Wt (N x K bf16) ----------
__global__ void transpose_cast_kernel(const float* __restrict__ W, unsigned short* __restrict__ Wt,
                                      int rows, int cols) {
    __shared__ float tile[32][33];           // +1 pad: conflict-free transpose
    int bx = blockIdx.x * 32;                // col block (n)
    int by = blockIdx.y * 32;                // row block (k)
    int tx = threadIdx.x;                    // 0..31
    int ty = threadIdx.y;                    // 0..7
    #pragma unroll
    for (int i = 0; i < 32; i += 8)
        tile[ty + i][tx] = W[(size_t)(by + ty + i) * cols + bx + tx];
    __syncthreads();
    #pragma unroll
    for (int i = 0; i < 32; i += 8)
        Wt[(size_t)(bx + ty + i) * rows + by + tx] = f2bf(tile[tx][ty + i]);
}

// ---------- bf16 MFMA GEMM: C = A (MxK) * Bt^T (Bt is NxK), + bias, epilogue OP ----------
// OP 0: q = elu(v)+1          -> bf16 out
// OP 1: k = (elu(v)+1)*mask   -> bf16 out
// OP 2: v = v*mask            -> bf16 out
// OP 3: final: v (+bias)      -> fp32 out
#define BMT 128
#define BNT 128
#define BKT 32

template<int OP>
__global__ __launch_bounds__(256, 2)
void gemm_bt_kernel(const unsigned short* __restrict__ A,
                    const unsigned short* __restrict__ Bt,
                    const float* __restrict__ bias,
                    const float* __restrict__ mask,
                    unsigned short* __restrict__ Cb,
                    float* __restrict__ Cf,
                    int M, int N, int K) {
    __shared__ __align__(16) unsigned short As[BMT * BKT];
    __shared__ __align__(16) unsigned short Bs[BNT * BKT];

    const int tid  = threadIdx.x;
    const int wave = tid >> 6;
    const int lane = tid & 63;
    const int m0 = blockIdx.x * BMT;
    const int n0 = blockIdx.y * BNT;
    const int wm = (wave >> 1) * 64;     // wave tile 64x64 inside 128x128
    const int wn = (wave & 1) * 64;
    const int quad  = lane >> 4;
    const int row16 = lane & 15;

    floatx4 acc[4][4] = {};

    const int sr    = wave * 32 + (lane >> 2);   // staging row (i=0 half)
    const int sslot = lane & 3;

    for (int k0 = 0; k0 < K; k0 += BKT) {
        // ---- stage A-tile (128x32) and Bt-tile (128x32) with XOR-swizzled chunks ----
        #pragma unroll
        for (int i = 0; i < 2; i++) {
            int r = sr + i * 16;
            int c = sslot ^ (r & 3) ^ ((r >> 2) & 3);
            async_load16(A  + (size_t)(m0 + r) * K + k0 + c * 8,
                         As + (size_t)(wave * 32 + i * 16) * 32);
            async_load16(Bt + (size_t)(n0 + r) * K + k0 + c * 8,
                         Bs + (size_t)(wave * 32 + i * 16) * 32);
        }
        __syncthreads();

        bf16x8 af[4], bfr[4];
        #pragma unroll
        for (int t = 0; t < 4; t++) {
            int ra = wm + t * 16 + row16;
            int sa = quad ^ (ra & 3) ^ ((ra >> 2) & 3);
            af[t]  = __builtin_bit_cast(bf16x8, *(const short8*)(As + ra * 32 + sa * 8));
            int rb = wn + t * 16 + row16;
            int sb = quad ^ (rb & 3) ^ ((rb >> 2) & 3);
            bfr[t] = __builtin_bit_cast(bf16x8, *(const short8*)(Bs + rb * 32 + sb * 8));
        }
        #pragma unroll
        for (int i = 0; i < 4; i++)
            #pragma unroll
            for (int j = 0; j < 4; j++)
                acc[i][j] = __builtin_amdgcn_mfma_f32_16x16x32_bf16(af[i], bfr[j], acc[i][j], 0, 0, 0);
        __syncthreads();
    }

    // ---- epilogue: D row = wm+i*16+quad*4+r, col = wn+j*16+row16 ----
    #pragma unroll
    for (int i = 0; i < 4; i++) {
        #pragma unroll
        for (int j = 0; j < 4; j++) {
            int col = n0 + wn + j * 16 + row16;
            float bv = bias[col];
            #pragma unroll
            for (int r = 0; r < 4; r++) {
                int row = m0 + wm + i * 16 + quad * 4 + r;
                float v = acc[i][j][r] + bv;
                if (OP == 0) {
                    v = (v > 0.f) ? (v + 1.f) : __expf(v);            // elu(v)+1
                } else if (OP == 1) {
                    v = ((v > 0.f) ? (v + 1.f) : __expf(v)) * mask[row];
                } else if (OP == 2) {
                    v = v * mask[row];
                }
                if (OP == 3) Cf[(size_t)row * N + col] = v;
                else         Cb[(size_t)row * N + col] = f2bf(v);
            }
        }
    }
}

// ---------- linear-attention scan (elementwise kv), chunked 3-pass ----------
#define SL   4096
#define SD   2048
#define SH   16
#define CHUNK 256
#define NCH   16   // SL / CHUNK

// Pass A: per-(b,h,chunk) partial sums of k and k*v over the chunk
__global__ void scan_partial_kernel(const unsigned short* __restrict__ k,
                                    const unsigned short* __restrict__ v,
                                    float* __restrict__ sumK, float* __restrict__ sumKV) {
    int blk = blockIdx.x;
    int c = blk & (NCH - 1), bh = blk >> 4;
    int b = bh >> 4, h = bh & (SH - 1);
    int lane = threadIdx.x;               // 64 lanes, each owns d=lane and d=lane+64
    size_t base = ((size_t)(b * SL + c * CHUNK)) * SD + h * 128 + lane;
    float s0 = 0.f, s1 = 0.f, sv0 = 0.f, sv1 = 0.f;
    for (int t = 0; t < CHUNK; t++) {
        float k0 = bf2f(k[base]), k1 = bf2f(k[base + 64]);
        float v0 = bf2f(v[base]), v1 = bf2f(v[base + 64]);
        s0 += k0; s1 += k1; sv0 += k0 * v0; sv1 += k1 * v1;
        base += SD;
    }
    size_t o = ((size_t)bh * NCH + c) * 128 + lane;
    sumK[o] = s0;  sumK[o + 64] = s1;
    sumKV[o] = sv0; sumKV[o + 64] = sv1;
}

// Pass B: exclusive scan of chunk sums along the chunk axis, per (b,h,d)
__global__ void scan_offsets_kernel(const float* __restrict__ sumK, const float* __restrict__ sumKV,
                                    float* __restrict__ offK, float* __restrict__ offKV) {
    int bh = blockIdx.x;
    int d  = threadIdx.x;   // 0..127
    float aK = 0.f, aKV = 0.f;
    for (int c = 0; c < NCH; c++) {
        size_t o = ((size_t)bh * NCH + c) * 128 + d;
        float sk = sumK[o], skv = sumKV[o];
        offK[o] = aK; offKV[o] = aKV;
        aK += sk; aKV += skv;
    }
}

// Pass C: within-chunk sequential scan + z reduction + output (bf16)
__global__ void scan_final_kernel(const unsigned short* __restrict__ q,
                                  const unsigned short* __restrict__ k,
                                  const unsigned short* __restrict__ v,
                                  const float* __restrict__ offK, const float* __restrict__ offKV,
                                  const float* __restrict__ mask,
                                  unsigned short* __restrict__ out) {
    int blk = blockIdx.x;
    int c = blk & (NCH - 1), bh = blk >> 4;
    int b = bh >> 4, h = bh & (SH - 1);
    int lane = threadIdx.x;
    size_t ob = ((size_t)bh * NCH + c) * 128 + lane;
    float kc0 = offK[ob],  kc1 = offK[ob + 64];
    float kv0 = offKV[ob], kv1 = offKV[ob + 64];
    size_t base = ((size_t)(b * SL + c * CHUNK)) * SD + h * 128 + lane;
    const float* mrow = mask + (size_t)b * SL + c * CHUNK;
    for (int t = 0; t < CHUNK; t++) {
        float kk0 = bf2f(k[base]), kk1 = bf2f(k[base + 64]);
        float vv0 = bf2f(v[base]), vv1 = bf2f(v[base + 64]);
        float qq0 = bf2f(q[base]), qq1 = bf2f(q[base + 64]);
        kc0 += kk0; kc1 += kk1;
        kv0 += kk0 * vv0; kv1 += kk1 * vv1;
        float p = qq0 * kc0 + qq1 * kc1;
        #pragma unroll
        for (int off = 32; off > 0; off >>= 1) p += __shfl_xor(p, off);
        float z = (p + EPS_F) * mrow[t];
        float inv = 1.0f / z;
        out[base]      = f2bf(qq0 * kv0 * inv);
        out[base + 64] = f2bf(qq1 * kv1 * inv);
        base += SD;
    }
}

// ---------- launcher ----------
extern "C" void kernel_launch(void* const* d_in, const int* in_sizes, int n_in,
                              void* d_out, int out_size, void* d_ws, size_t ws_size,
                              hipStream_t stream) {
    const float* x  = (const float*)d_in[0];
    const float* am = (const float*)d_in[1];
    const float* Wq = (const float*)d_in[2];
    const float* bq = (const float*)d_in[3];
    const float* Wk = (const float*)d_in[4];
    const float* bk = (const float*)d_in[5];
    const float* Wv = (const float*)d_in[6];
    const float* bv = (const float*)d_in[7];
    const float* Wo = (const float*)d_in[8];
    const float* bo = (const float*)d_in[9];
    float* out = (float*)d_out;

    const int Bb = 4, L = 4096, D = 2048;
    const int M = Bb * L;                      // 16384
    const size_t MD = (size_t)M * D;           // 33,554,432

    // workspace carve-up (~354 MB)
    char* w = (char*)d_ws;
    unsigned short* xb    = (unsigned short*)w; w += MD * 2;
    unsigned short* qb    = (unsigned short*)w; w += MD * 2;
    unsigned short* kb    = (unsigned short*)w; w += MD * 2;
    unsigned short* vb    = (unsigned short*)w; w += MD * 2;
    unsigned short* attnb = (unsigned short*)w; w += MD * 2;
    unsigned short* WqT   = (unsigned short*)w; w += (size_t)D * D * 2;
    unsigned short* WkT   = (unsigned short*)w; w += (size_t)D * D * 2;
    unsigned short* WvT   = (unsigned short*)w; w += (size_t)D * D * 2;
    unsigned short* WoT   = (unsigned short*)w; w += (size_t)D * D * 2;
    float* sumK  = (float*)w; w += 64 * NCH * 128 * 4;
    float* sumKV = (float*)w; w += 64 * NCH * 128 * 4;
    float* offK  = (float*)w; w += 64 * NCH * 128 * 4;
    float* offKV = (float*)w; w += 64 * NCH * 128 * 4;

    // 1) casts / transposes
    int n4 = (int)(MD / 4);
    cast_x_kernel<<<(n4 + 255) / 256, 256, 0, stream>>>(x, xb, n4);
    dim3 tb(32, 8);
    dim3 tg(D / 32, D / 32);
    transpose_cast_kernel<<<tg, tb, 0, stream>>>(Wq, WqT, D, D);
    transpose_cast_kernel<<<tg, tb, 0, stream>>>(Wk, WkT, D, D);
    transpose_cast_kernel<<<tg, tb, 0, stream>>>(Wv, WvT, D, D);
    transpose_cast_kernel<<<tg, tb, 0, stream>>>(Wo, WoT, D, D);

    // 2) QKV projections with fused epilogues
    dim3 gg(M / BMT, D / BNT);
    gemm_bt_kernel<0><<<gg, 256, 0, stream>>>(xb, WqT, bq, nullptr, qb, nullptr, M, D, D);
    gemm_bt_kernel<1><<<gg, 256, 0, stream>>>(xb, WkT, bk, am,      kb, nullptr, M, D, D);
    gemm_bt_kernel<2><<<gg, 256, 0, stream>>>(xb, WvT, bv, am,      vb, nullptr, M, D, D);

    // 3) chunked linear-attention scan
    scan_partial_kernel<<<64 * NCH, 64, 0, stream>>>(kb, vb, sumK, sumKV);
    scan_offsets_kernel<<<64, 128, 0, stream>>>(sumK, sumKV, offK, offKV);
    scan_final_kernel<<<64 * NCH, 64, 0, stream>>>(qb, kb, vb, offK, offKV, am, attnb);

    // 4) output projection -> fp32 d_out
    gemm_bt_kernel<3><<<gg, 256, 0, stream>>>(attnb, WoT, bo, nullptr, nullptr, out, M, D, D);
}

// Round 2
// 1032.807 us; speedup vs baseline: 1.1226x; 1.1226x over previous
//
#include <hip/hip_runtime.h>
#include <cstdint>
#include <cstddef>

#define EPS_F 1e-6f

// ---------- bf16 helpers ----------
__device__ inline unsigned short f2bf(float f) {
    union { float f; unsigned u; } v; v.f = f;
    unsigned r = v.u + 0x7fffu + ((v.u >> 16) & 1u);   // RNE
    return (unsigned short)(r >> 16);
}
__device__ inline float bf2f(unsigned u16) {           // low 16 bits used
    union { unsigned u; float f; } v; v.u = u16 << 16; return v.f;
}

typedef __attribute__((ext_vector_type(8))) __bf16 bf16x8;
typedef __attribute__((ext_vector_type(8))) short short8;
typedef __attribute__((ext_vector_type(4))) float floatx4;

__device__ inline void async_load16(const void* g, void* l) {
    __builtin_amdgcn_global_load_lds((const __attribute__((address_space(1))) void*)g,
                                     (__attribute__((address_space(3))) void*)l,
                                     16, 0, 0);
}

// ---------- cast fp32 -> bf16, 8 elems/thread (16B store) ----------
__global__ void cast_x_kernel(const float* __restrict__ in, unsigned short* __restrict__ out, int n8) {
    int i = blockIdx.x * blockDim.x + threadIdx.x;
    if (i < n8) {
        float4 a = ((const float4*)in)[2 * i];
        float4 b = ((const float4*)in)[2 * i + 1];
        short8 o;
        o[0] = (short)f2bf(a.x); o[1] = (short)f2bf(a.y);
        o[2] = (short)f2bf(a.z); o[3] = (short)f2bf(a.w);
        o[4] = (short)f2bf(b.x); o[5] = (short)f2bf(b.y);
        o[6] = (short)f2bf(b.z); o[7] = (short)f2bf(b.w);
        ((short8*)out)[i] = o;
    }
}

// ---------- transpose + cast 4 weights in one dispatch (blockIdx.z selects) ----------
// W (n x n fp32 row-major) -> Wt (n x n bf16), Wt[j][i] = W[i][j]
__global__ void transpose_cast_kernel(const float* __restrict__ W0, const float* __restrict__ W1,
                                      const float* __restrict__ W2, const float* __restrict__ W3,
                                      unsigned short* __restrict__ WtBase, int n) {
    const float* W = (blockIdx.z == 0) ? W0 : (blockIdx.z == 1) ? W1 : (blockIdx.z == 2) ? W2 : W3;
    unsigned short* Wt = WtBase + (size_t)blockIdx.z * n * n;
    __shared__ float tile[32][33];
    int bx = blockIdx.x * 32;
    int by = blockIdx.y * 32;
    int tx = threadIdx.x;        // 0..31
    int ty = threadIdx.y;        // 0..7
    #pragma unroll
    for (int i = 0; i < 32; i += 8)
        tile[ty + i][tx] = W[(size_t)(by + ty + i) * n + bx + tx];
    __syncthreads();
    #pragma unroll
    for (int i = 0; i < 32; i += 8)
        Wt[(size_t)(bx + ty + i) * n + by + tx] = f2bf(tile[tx][ty + i]);
}

// ---------- bf16 MFMA GEMM core ----------
// FINAL=0: fused QKV. Bt is (3*D x K) = [WqT;WkT;WvT]; epilogue per n-block:
//   mat 0: q=elu(v+bq)+1 ; mat 1: k=(elu(v+bk)+1)*mask ; mat 2: v=(v+bv)*mask ; bf16 out
// FINAL=1: out = A*WoT^T + bo, fp32 out
#define BMT 128
#define BNT 128
#define BKT 32
#define DMODEL 2048

template<int FINAL>
__global__ __launch_bounds__(256, 2)
void gemm_kernel(const unsigned short* __restrict__ A,
                 const unsigned short* __restrict__ Bt,
                 const float* __restrict__ b0, const float* __restrict__ b1,
                 const float* __restrict__ b2,
                 const float* __restrict__ mask,
                 unsigned short* __restrict__ qo, unsigned short* __restrict__ ko,
                 unsigned short* __restrict__ vo,
                 float* __restrict__ Cf,
                 int M, int K) {
    __shared__ __align__(16) unsigned short As[BMT * BKT];
    __shared__ __align__(16) unsigned short Bs[BNT * BKT];

    const int tid  = threadIdx.x;
    const int wave = tid >> 6;
    const int lane = tid & 63;
    const int m0    = blockIdx.x * BMT;
    const int nglob = blockIdx.y * BNT;
    int mat, n0;
    const float* bias;
    unsigned short* Cb = nullptr;
    if (FINAL) {
        mat = 0; n0 = nglob; bias = b0;
    } else {
        mat  = nglob >> 11;            // /DMODEL
        n0   = nglob & (DMODEL - 1);
        bias = (mat == 0) ? b0 : (mat == 1) ? b1 : b2;
        Cb   = (mat == 0) ? qo : (mat == 1) ? ko : vo;
    }
    const int wm = (wave >> 1) * 64;
    const int wn = (wave & 1) * 64;
    const int quad  = lane >> 4;
    const int row16 = lane & 15;

    floatx4 acc[4][4] = {};

    const int sr    = wave * 32 + (lane >> 2);
    const int sslot = lane & 3;

    for (int k0 = 0; k0 < K; k0 += BKT) {
        #pragma unroll
        for (int i = 0; i < 2; i++) {
            int r = sr + i * 16;
            int c = sslot ^ (r & 3) ^ ((r >> 2) & 3);
            async_load16(A  + (size_t)(m0 + r) * K + k0 + c * 8,
                         As + (size_t)(wave * 32 + i * 16) * 32);
            async_load16(Bt + (size_t)(nglob + r) * K + k0 + c * 8,
                         Bs + (size_t)(wave * 32 + i * 16) * 32);
        }
        __syncthreads();

        bf16x8 af[4], bfr[4];
        #pragma unroll
        for (int t = 0; t < 4; t++) {
            int ra = wm + t * 16 + row16;
            int sa = quad ^ (ra & 3) ^ ((ra >> 2) & 3);
            af[t]  = __builtin_bit_cast(bf16x8, *(const short8*)(As + ra * 32 + sa * 8));
            int rb = wn + t * 16 + row16;
            int sb = quad ^ (rb & 3) ^ ((rb >> 2) & 3);
            bfr[t] = __builtin_bit_cast(bf16x8, *(const short8*)(Bs + rb * 32 + sb * 8));
        }
        #pragma unroll
        for (int i = 0; i < 4; i++)
            #pragma unroll
            for (int j = 0; j < 4; j++)
                acc[i][j] = __builtin_amdgcn_mfma_f32_16x16x32_bf16(af[i], bfr[j], acc[i][j], 0, 0, 0);
        __syncthreads();
    }

    // epilogue: D row = wm+i*16+quad*4+r, col = wn+j*16+row16
    float bcache[4];
    #pragma unroll
    for (int j = 0; j < 4; j++) bcache[j] = bias[n0 + wn + j * 16 + row16];
    #pragma unroll
    for (int i = 0; i < 4; i++) {
        #pragma unroll
        for (int r = 0; r < 4; r++) {
            int row = m0 + wm + i * 16 + quad * 4 + r;
            float mr = 1.0f;
            if (!FINAL && mat >= 1) mr = mask[row];
            #pragma unroll
            for (int j = 0; j < 4; j++) {
                int col = n0 + wn + j * 16 + row16;
                float v = acc[i][j][r] + bcache[j];
                if (FINAL) {
                    Cf[(size_t)row * DMODEL + col] = v;
                } else {
                    if (mat <= 1) v = (v > 0.f) ? (v + 1.f) : __expf(v);  // elu+1
                    v *= mr;
                    Cb[(size_t)row * DMODEL + col] = f2bf(v);
                }
            }
        }
    }
}

// ---------- linear-attention scan (elementwise kv), chunked 3-pass ----------
#define SL    4096
#define SD    2048
#define SH    16
#define CHUNK 64
#define NCH   64   // SL / CHUNK

// Pass A: per-(b,h,chunk) partial sums of k and k*v; lane owns d=2*lane,2*lane+1
__global__ void scan_partial_kernel(const unsigned short* __restrict__ k,
                                    const unsigned short* __restrict__ v,
                                    float* __restrict__ sumK, float* __restrict__ sumKV) {
    int blk = blockIdx.x;
    int c = blk & (NCH - 1), bh = blk >> 6;
    int b = bh >> 4, h = bh & (SH - 1);
    int lane = threadIdx.x;
    size_t base = ((size_t)(b * SL + c * CHUNK)) * SD + h * 128 + 2 * lane;
    float s0 = 0.f, s1 = 0.f, sv0 = 0.f, sv1 = 0.f;
    for (int t = 0; t < CHUNK; t++) {
        unsigned kw = *(const unsigned*)(k + base);
        unsigned vw = *(const unsigned*)(v + base);
        float k0 = bf2f(kw & 0xffff), k1 = bf2f(kw >> 16);
        float v0 = bf2f(vw & 0xffff), v1 = bf2f(vw >> 16);
        s0 += k0; s1 += k1; sv0 += k0 * v0; sv1 += k1 * v1;
        base += SD;
    }
    size_t o = ((size_t)bh * NCH + c) * 128 + 2 * lane;
    ((float2*)(sumK  + o))[0] = make_float2(s0, s1);
    ((float2*)(sumKV + o))[0] = make_float2(sv0, sv1);
}

// Pass B: exclusive scan of chunk sums along chunk axis, per (b,h,d)
__global__ void scan_offsets_kernel(const float* __restrict__ sumK, const float* __restrict__ sumKV,
                                    float* __restrict__ offK, float* __restrict__ offKV) {
    int bh = blockIdx.x;
    int d  = threadIdx.x;   // 0..127
    float aK = 0.f, aKV = 0.f;
    for (int c = 0; c < NCH; c++) {
        size_t o = ((size_t)bh * NCH + c) * 128 + d;
        float sk = sumK[o], skv = sumKV[o];
        offK[o] = aK; offKV[o] = aKV;
        aK += sk; aKV += skv;
    }
}

// Pass C: within-chunk sequential scan + z reduction + bf16 output
__global__ void scan_final_kernel(const unsigned short* __restrict__ q,
                                  const unsigned short* __restrict__ k,
                                  const unsigned short* __restrict__ v,
                                  const float* __restrict__ offK, const float* __restrict__ offKV,
                                  const float* __restrict__ mask,
                                  unsigned short* __restrict__ out) {
    int blk = blockIdx.x;
    int c = blk & (NCH - 1), bh = blk >> 6;
    int b = bh >> 4, h = bh & (SH - 1);
    int lane = threadIdx.x;
    size_t ob = ((size_t)bh * NCH + c) * 128 + 2 * lane;
    float2 kcv = ((const float2*)(offK  + ob))[0];
    float2 kvv = ((const float2*)(offKV + ob))[0];
    float kc0 = kcv.x, kc1 = kcv.y, kv0 = kvv.x, kv1 = kvv.y;
    size_t base = ((size_t)(b * SL + c * CHUNK)) * SD + h * 128 + 2 * lane;
    const float* mrow = mask + (size_t)b * SL + c * CHUNK;
    for (int t = 0; t < CHUNK; t++) {
        unsigned kw = *(const unsigned*)(k + base);
        unsigned vw = *(const unsigned*)(v + base);
        unsigned qw = *(const unsigned*)(q + base);
        float kk0 = bf2f(kw & 0xffff), kk1 = bf2f(kw >> 16);
        float vv0 = bf2f(vw & 0xffff), vv1 = bf2f(vw >> 16);
        float qq0 = bf2f(qw & 0xffff), qq1 = bf2f(qw >> 16);
        kc0 += kk0; kc1 += kk1;
        kv0 += kk0 * vv0; kv1 += kk1 * vv1;
        float p = qq0 * kc0 + qq1 * kc1;
        #pragma unroll
        for (int off = 32; off > 0; off >>= 1) p += __shfl_xor(p, off);
        float z = (p + EPS_F) * mrow[t];
        float inv = 1.0f / z;
        unsigned o0 = f2bf(qq0 * kv0 * inv);
        unsigned o1 = f2bf(qq1 * kv1 * inv);
        *(unsigned*)(out + base) = o0 | (o1 << 16);
        base += SD;
    }
}

// ---------- launcher ----------
extern "C" void kernel_launch(void* const* d_in, const int* in_sizes, int n_in,
                              void* d_out, int out_size, void* d_ws, size_t ws_size,
                              hipStream_t stream) {
    const float* x  = (const float*)d_in[0];
    const float* am = (const float*)d_in[1];
    const float* Wq = (const float*)d_in[2];
    const float* bq = (const float*)d_in[3];
    const float* Wk = (const float*)d_in[4];
    const float* bk = (const float*)d_in[5];
    const float* Wv = (const float*)d_in[6];
    const float* bv = (const float*)d_in[7];
    const float* Wo = (const float*)d_in[8];
    const float* bo = (const float*)d_in[9];
    float* out = (float*)d_out;

    const int Bb = 4, L = 4096, D = 2048;
    const int M = Bb * L;                       // 16384
    const size_t MD = (size_t)M * D;            // 33,554,432

    // workspace carve-up (~310 MB). attn aliases xb (xb dead after QKV GEMM).
    char* w = (char*)d_ws;
    unsigned short* xb    = (unsigned short*)w; w += MD * 2;
    unsigned short* qb    = (unsigned short*)w; w += MD * 2;
    unsigned short* kb    = (unsigned short*)w; w += MD * 2;
    unsigned short* vb    = (unsigned short*)w; w += MD * 2;
    unsigned short* WT    = (unsigned short*)w; w += (size_t)4 * D * D * 2; // [WqT;WkT;WvT;WoT]
    float* sumK  = (float*)w; w += (size_t)64 * NCH * 128 * 4;
    float* sumKV = (float*)w; w += (size_t)64 * NCH * 128 * 4;
    float* offK  = (float*)w; w += (size_t)64 * NCH * 128 * 4;
    float* offKV = (float*)w; w += (size_t)64 * NCH * 128 * 4;
    unsigned short* attnb = xb;                 // alias

    // 1) casts / transposes
    int n8 = (int)(MD / 8);
    cast_x_kernel<<<(n8 + 255) / 256, 256, 0, stream>>>(x, xb, n8);
    dim3 tb(32, 8);
    dim3 tg(D / 32, D / 32, 4);
    transpose_cast_kernel<<<tg, tb, 0, stream>>>(Wq, Wk, Wv, Wo, WT, D);

    // 2) fused QKV projection (N = 3*D), epilogues fused
    dim3 gq(M / BMT, 3 * D / BNT);
    gemm_kernel<0><<<gq, 256, 0, stream>>>(xb, WT, bq, bk, bv, am, qb, kb, vb, nullptr, M, D);

    // 3) chunked linear-attention scan
    scan_partial_kernel<<<64 * NCH, 64, 0, stream>>>(kb, vb, sumK, sumKV);
    scan_offsets_kernel<<<64, 128, 0, stream>>>(sumK, sumKV, offK, offKV);
    scan_final_kernel<<<64 * NCH, 64, 0, stream>>>(qb, kb, vb, offK, offKV, am, attnb);

    // 4) output projection -> fp32 d_out
    dim3 go(M / BMT, D / BNT);
    gemm_kernel<1><<<go, 256, 0, stream>>>(attnb, WT + (size_t)3 * D * D, bo, nullptr, nullptr,
                                           nullptr, nullptr, nullptr, nullptr, out, M, D);
}

// Round 3
// 899.740 us; speedup vs baseline: 1.2886x; 1.1479x over previous
//
#include <hip/hip_runtime.h>
#include <cstdint>
#include <cstddef>

#define EPS_F 1e-6f

// ---------- bf16 helpers ----------
__device__ inline unsigned short f2bf(float f) {
    union { float f; unsigned u; } v; v.f = f;
    unsigned r = v.u + 0x7fffu + ((v.u >> 16) & 1u);   // RNE
    return (unsigned short)(r >> 16);
}
__device__ inline float bf2f(unsigned u16) {           // low 16 bits used
    union { unsigned u; float f; } v; v.u = u16 << 16; return v.f;
}

typedef __attribute__((ext_vector_type(8))) __bf16 bf16x8;
typedef __attribute__((ext_vector_type(8))) short short8;
typedef __attribute__((ext_vector_type(8))) unsigned short ushort8;
typedef __attribute__((ext_vector_type(4))) float floatx4;

__device__ inline void async_load16(const void* g, void* l) {
    __builtin_amdgcn_global_load_lds((const __attribute__((address_space(1))) void*)g,
                                     (__attribute__((address_space(3))) void*)l,
                                     16, 0, 0);
}

// ---------- cast fp32 -> bf16, 8 elems/thread (16B store) ----------
__global__ void cast_x_kernel(const float* __restrict__ in, unsigned short* __restrict__ out, int n8) {
    int i = blockIdx.x * blockDim.x + threadIdx.x;
    if (i < n8) {
        float4 a = ((const float4*)in)[2 * i];
        float4 b = ((const float4*)in)[2 * i + 1];
        short8 o;
        o[0] = (short)f2bf(a.x); o[1] = (short)f2bf(a.y);
        o[2] = (short)f2bf(a.z); o[3] = (short)f2bf(a.w);
        o[4] = (short)f2bf(b.x); o[5] = (short)f2bf(b.y);
        o[6] = (short)f2bf(b.z); o[7] = (short)f2bf(b.w);
        ((short8*)out)[i] = o;
    }
}

// ---------- transpose + cast 4 weights in one dispatch (blockIdx.z selects) ----------
__global__ void transpose_cast_kernel(const float* __restrict__ W0, const float* __restrict__ W1,
                                      const float* __restrict__ W2, const float* __restrict__ W3,
                                      unsigned short* __restrict__ WtBase, int n) {
    const float* W = (blockIdx.z == 0) ? W0 : (blockIdx.z == 1) ? W1 : (blockIdx.z == 2) ? W2 : W3;
    unsigned short* Wt = WtBase + (size_t)blockIdx.z * n * n;
    __shared__ float tile[32][33];
    int bx = blockIdx.x * 32;
    int by = blockIdx.y * 32;
    int tx = threadIdx.x;        // 0..31
    int ty = threadIdx.y;        // 0..7
    #pragma unroll
    for (int i = 0; i < 32; i += 8)
        tile[ty + i][tx] = W[(size_t)(by + ty + i) * n + bx + tx];
    __syncthreads();
    #pragma unroll
    for (int i = 0; i < 32; i += 8)
        Wt[(size_t)(bx + ty + i) * n + by + tx] = f2bf(tile[tx][ty + i]);
}

// ---------- bf16 MFMA GEMM core, BK=64 (half the barrier drains vs BK=32) ----------
// FINAL=0: fused QKV. Bt is (3*D x K) = [WqT;WkT;WvT]; epilogue per n-block:
//   mat 0: q=elu(v+bq)+1 ; mat 1: k=(elu(v+bk)+1)*mask ; mat 2: v=(v+bv)*mask ; bf16 out
// FINAL=1: out = A*WoT^T + bo, fp32 out
#define BMT 128
#define BNT 128
#define BKT 64
#define DMODEL 2048

template<int FINAL>
__global__ __launch_bounds__(256, 2)
void gemm_kernel(const unsigned short* __restrict__ A,
                 const unsigned short* __restrict__ Bt,
                 const float* __restrict__ b0, const float* __restrict__ b1,
                 const float* __restrict__ b2,
                 const float* __restrict__ mask,
                 unsigned short* __restrict__ qo, unsigned short* __restrict__ ko,
                 unsigned short* __restrict__ vo,
                 float* __restrict__ Cf,
                 int M, int K) {
    // 128 rows x 64 cols bf16 = 16KB each; rows are 8 chunks of 16B.
    // LDS slot (r, c) holds global chunk (c ^ (r&7))  -> breaks power-of-2 bank stride.
    __shared__ __align__(16) unsigned short As[BMT * BKT];
    __shared__ __align__(16) unsigned short Bs[BNT * BKT];

    const int tid  = threadIdx.x;
    const int wave = tid >> 6;
    const int lane = tid & 63;
    const int m0    = blockIdx.x * BMT;
    const int nglob = blockIdx.y * BNT;
    int mat, n0;
    const float* bias;
    unsigned short* Cb = nullptr;
    if (FINAL) {
        mat = 0; n0 = nglob; bias = b0;
    } else {
        mat  = nglob >> 11;            // /DMODEL
        n0   = nglob & (DMODEL - 1);
        bias = (mat == 0) ? b0 : (mat == 1) ? b1 : b2;
        Cb   = (mat == 0) ? qo : (mat == 1) ? ko : vo;
    }
    const int wm = (wave >> 1) * 64;
    const int wn = (wave & 1) * 64;
    const int quad  = lane >> 4;
    const int row16 = lane & 15;

    floatx4 acc[4][4] = {};

    // staging geometry: per matrix 1024 chunks = 128 rows x 8; 4 batches of 64 per wave
    const int srow_lo = lane >> 3;                 // 0..7 within batch
    const int schunk  = lane & 7;

    for (int k0 = 0; k0 < K; k0 += BKT) {
        #pragma unroll
        for (int i = 0; i < 4; i++) {
            int slot_base = wave * 256 + i * 64;          // wave-uniform LDS base (x16B)
            int r  = wave * 32 + i * 8 + srow_lo;         // tile row for this lane
            int cg = schunk ^ (r & 7);                    // global chunk feeding this slot
            const unsigned short* ga = A  + (size_t)(m0 + r) * K + k0 + cg * 8;
            const unsigned short* gb = Bt + (size_t)(nglob + r) * K + k0 + cg * 8;
            async_load16(ga, As + (size_t)slot_base * 8);
            async_load16(gb, Bs + (size_t)slot_base * 8);
        }
        __syncthreads();

        #pragma unroll
        for (int kk = 0; kk < 2; kk++) {                  // two 32-wide k-windows
            bf16x8 af[4], bfr[4];
            #pragma unroll
            for (int t = 0; t < 4; t++) {
                int ra = wm + t * 16 + row16;
                int ca = (kk * 4 + quad) ^ (ra & 7);
                af[t]  = __builtin_bit_cast(bf16x8, *(const short8*)(As + (size_t)ra * 64 + ca * 8));
                int rb = wn + t * 16 + row16;
                int cb = (kk * 4 + quad) ^ (rb & 7);
                bfr[t] = __builtin_bit_cast(bf16x8, *(const short8*)(Bs + (size_t)rb * 64 + cb * 8));
            }
            #pragma unroll
            for (int i = 0; i < 4; i++)
                #pragma unroll
                for (int j = 0; j < 4; j++)
                    acc[i][j] = __builtin_amdgcn_mfma_f32_16x16x32_bf16(af[i], bfr[j], acc[i][j], 0, 0, 0);
        }
        __syncthreads();
    }

    // epilogue: D row = wm+i*16+quad*4+r, col = wn+j*16+row16
    float bcache[4];
    #pragma unroll
    for (int j = 0; j < 4; j++) bcache[j] = bias[n0 + wn + j * 16 + row16];
    #pragma unroll
    for (int i = 0; i < 4; i++) {
        #pragma unroll
        for (int r = 0; r < 4; r++) {
            int row = m0 + wm + i * 16 + quad * 4 + r;
            float mr = 1.0f;
            if (!FINAL && mat >= 1) mr = mask[row];
            #pragma unroll
            for (int j = 0; j < 4; j++) {
                int col = n0 + wn + j * 16 + row16;
                float v = acc[i][j][r] + bcache[j];
                if (FINAL) {
                    Cf[(size_t)row * DMODEL + col] = v;
                } else {
                    if (mat <= 1) v = (v > 0.f) ? (v + 1.f) : __expf(v);  // elu+1
                    v *= mr;
                    Cb[(size_t)row * DMODEL + col] = f2bf(v);
                }
            }
        }
    }
}

// ---------- linear-attention scan (elementwise kv), chunked 3-pass ----------
#define SL    4096
#define SD    2048
#define SH    16
#define CHUNK 64
#define NCH   64   // SL / CHUNK

// Pass A: per-(b,h,chunk) partial sums. lane = tg*16+dg: 4 t-rows in flight,
// 16B/lane loads; summation is order-free so cross-lane combine at the end.
__global__ void scan_partial_kernel(const unsigned short* __restrict__ k,
                                    const unsigned short* __restrict__ v,
                                    float* __restrict__ sumK, float* __restrict__ sumKV) {
    int blk = blockIdx.x;
    int c = blk & (NCH - 1), bh = blk >> 6;
    int b = bh >> 4, h = bh & (SH - 1);
    int lane = threadIdx.x;
    int tg = lane >> 4, dg = lane & 15;
    size_t base = ((size_t)(b * SL + c * CHUNK + tg)) * SD + h * 128 + dg * 8;
    float sk[8] = {0.f, 0.f, 0.f, 0.f, 0.f, 0.f, 0.f, 0.f};
    float skv[8] = {0.f, 0.f, 0.f, 0.f, 0.f, 0.f, 0.f, 0.f};
    for (int it = 0; it < CHUNK / 4; it++) {
        ushort8 kw = *(const ushort8*)(k + base);
        ushort8 vw = *(const ushort8*)(v + base);
        #pragma unroll
        for (int j = 0; j < 8; j++) {
            float kf = bf2f(kw[j]);
            float vf = bf2f(vw[j]);
            sk[j] += kf; skv[j] += kf * vf;
        }
        base += (size_t)4 * SD;
    }
    #pragma unroll
    for (int j = 0; j < 8; j++) {
        sk[j]  += __shfl_xor(sk[j], 16);  sk[j]  += __shfl_xor(sk[j], 32);
        skv[j] += __shfl_xor(skv[j], 16); skv[j] += __shfl_xor(skv[j], 32);
    }
    if (tg == 0) {
        size_t o = ((size_t)bh * NCH + c) * 128 + dg * 8;
        *(float4*)(sumK  + o)     = make_float4(sk[0], sk[1], sk[2], sk[3]);
        *(float4*)(sumK  + o + 4) = make_float4(sk[4], sk[5], sk[6], sk[7]);
        *(float4*)(sumKV + o)     = make_float4(skv[0], skv[1], skv[2], skv[3]);
        *(float4*)(sumKV + o + 4) = make_float4(skv[4], skv[5], skv[6], skv[7]);
    }
}

// Pass B: exclusive scan of chunk sums along chunk axis, per (b,h,d)
__global__ void scan_offsets_kernel(const float* __restrict__ sumK, const float* __restrict__ sumKV,
                                    float* __restrict__ offK, float* __restrict__ offKV) {
    int bh = blockIdx.x;
    int d  = threadIdx.x;   // 0..127
    float aK = 0.f, aKV = 0.f;
    for (int c = 0; c < NCH; c++) {
        size_t o = ((size_t)bh * NCH + c) * 128 + d;
        float sk = sumK[o], skv = sumKV[o];
        offK[o] = aK; offKV[o] = aKV;
        aK += sk; aKV += skv;
    }
}

// Pass C: within-chunk sequential scan, 4-timestep batches: 12 loads in flight,
// 4 interleaved shuffle-reduction trees amortize the 6-step latency.
__global__ void scan_final_kernel(const unsigned short* __restrict__ q,
                                  const unsigned short* __restrict__ k,
                                  const unsigned short* __restrict__ v,
                                  const float* __restrict__ offK, const float* __restrict__ offKV,
                                  const float* __restrict__ mask,
                                  unsigned short* __restrict__ out) {
    int blk = blockIdx.x;
    int c = blk & (NCH - 1), bh = blk >> 6;
    int b = bh >> 4, h = bh & (SH - 1);
    int lane = threadIdx.x;
    size_t ob = ((size_t)bh * NCH + c) * 128 + 2 * lane;
    float2 kcv = *(const float2*)(offK  + ob);
    float2 kvv = *(const float2*)(offKV + ob);
    float kc0 = kcv.x, kc1 = kcv.y, kv0 = kvv.x, kv1 = kvv.y;
    size_t base = ((size_t)(b * SL + c * CHUNK)) * SD + h * 128 + 2 * lane;
    const float* mrow = mask + (size_t)b * SL + c * CHUNK;
    for (int s = 0; s < CHUNK / 4; s++) {
        unsigned kw[4], vw[4], qw[4];
        #pragma unroll
        for (int u = 0; u < 4; u++) {
            size_t a = base + (size_t)u * SD;
            kw[u] = *(const unsigned*)(k + a);
            vw[u] = *(const unsigned*)(v + a);
            qw[u] = *(const unsigned*)(q + a);
        }
        float p[4], n0[4], n1[4];
        #pragma unroll
        for (int u = 0; u < 4; u++) {
            float kk0 = bf2f(kw[u] & 0xffff), kk1 = bf2f(kw[u] >> 16);
            float vv0 = bf2f(vw[u] & 0xffff), vv1 = bf2f(vw[u] >> 16);
            float qq0 = bf2f(qw[u] & 0xffff), qq1 = bf2f(qw[u] >> 16);
            kc0 += kk0; kc1 += kk1;
            kv0 += kk0 * vv0; kv1 += kk1 * vv1;
            p[u]  = qq0 * kc0 + qq1 * kc1;
            n0[u] = qq0 * kv0; n1[u] = qq1 * kv1;
        }
        #pragma unroll
        for (int off = 32; off > 0; off >>= 1) {
            #pragma unroll
            for (int u = 0; u < 4; u++) p[u] += __shfl_xor(p[u], off);
        }
        #pragma unroll
        for (int u = 0; u < 4; u++) {
            float z = (p[u] + EPS_F) * mrow[s * 4 + u];
            float inv = 1.0f / z;
            unsigned o0 = f2bf(n0[u] * inv);
            unsigned o1 = f2bf(n1[u] * inv);
            *(unsigned*)(out + base + (size_t)u * SD) = o0 | (o1 << 16);
        }
        base += (size_t)4 * SD;
    }
}

// ---------- launcher ----------
extern "C" void kernel_launch(void* const* d_in, const int* in_sizes, int n_in,
                              void* d_out, int out_size, void* d_ws, size_t ws_size,
                              hipStream_t stream) {
    const float* x  = (const float*)d_in[0];
    const float* am = (const float*)d_in[1];
    const float* Wq = (const float*)d_in[2];
    const float* bq = (const float*)d_in[3];
    const float* Wk = (const float*)d_in[4];
    const float* bk = (const float*)d_in[5];
    const float* Wv = (const float*)d_in[6];
    const float* bv = (const float*)d_in[7];
    const float* Wo = (const float*)d_in[8];
    const float* bo = (const float*)d_in[9];
    float* out = (float*)d_out;

    const int Bb = 4, L = 4096, D = 2048;
    const int M = Bb * L;                       // 16384
    const size_t MD = (size_t)M * D;            // 33,554,432

    // workspace carve-up (~310 MB). attn aliases xb (xb dead after QKV GEMM).
    char* w = (char*)d_ws;
    unsigned short* xb    = (unsigned short*)w; w += MD * 2;
    unsigned short* qb    = (unsigned short*)w; w += MD * 2;
    unsigned short* kb    = (unsigned short*)w; w += MD * 2;
    unsigned short* vb    = (unsigned short*)w; w += MD * 2;
    unsigned short* WT    = (unsigned short*)w; w += (size_t)4 * D * D * 2; // [WqT;WkT;WvT;WoT]
    float* sumK  = (float*)w; w += (size_t)64 * NCH * 128 * 4;
    float* sumKV = (float*)w; w += (size_t)64 * NCH * 128 * 4;
    float* offK  = (float*)w; w += (size_t)64 * NCH * 128 * 4;
    float* offKV = (float*)w; w += (size_t)64 * NCH * 128 * 4;
    unsigned short* attnb = xb;                 // alias

    // 1) casts / transposes
    int n8 = (int)(MD / 8);
    cast_x_kernel<<<(n8 + 255) / 256, 256, 0, stream>>>(x, xb, n8);
    dim3 tb(32, 8);
    dim3 tg(D / 32, D / 32, 4);
    transpose_cast_kernel<<<tg, tb, 0, stream>>>(Wq, Wk, Wv, Wo, WT, D);

    // 2) fused QKV projection (N = 3*D), epilogues fused
    dim3 gq(M / BMT, 3 * D / BNT);
    gemm_kernel<0><<<gq, 256, 0, stream>>>(xb, WT, bq, bk, bv, am, qb, kb, vb, nullptr, M, D);

    // 3) chunked linear-attention scan
    scan_partial_kernel<<<64 * NCH, 64, 0, stream>>>(kb, vb, sumK, sumKV);
    scan_offsets_kernel<<<64, 128, 0, stream>>>(sumK, sumKV, offK, offKV);
    scan_final_kernel<<<64 * NCH, 64, 0, stream>>>(qb, kb, vb, offK, offKV, am, attnb);

    // 4) output projection -> fp32 d_out
    dim3 go(M / BMT, D / BNT);
    gemm_kernel<1><<<go, 256, 0, stream>>>(attnb, WT + (size_t)3 * D * D, bo, nullptr, nullptr,
                                           nullptr, nullptr, nullptr, nullptr, out, M, D);
}